// Round 4
// baseline (555.124 us; speedup 1.0000x reference)
//
#include <hip/hip_runtime.h>
#include <math.h>

#define N_NODES 100000
#define N_EDGES 1600000
#define OUTC 40
#define PAIRS40 20

#define NC 32                       // edge chunks
#define CHUNK (N_EDGES / NC)        // 50000 exact

// histogram pass: 16-bit packed counters, 32768 nodes/range
#define RANGE_H 32768
#define NR_H 4                      // 4*32768 = 131072 >= N
#define NPAD_H (NR_H * RANGE_H)     // 131072

// fill pass: 32-bit position counters, 16384 nodes/range
#define RANGE_F 16384
#define NR_F 7                      // 7*16384 = 114688 >= N

#define SCAN_BLOCK 1024
#define SCAN_NBLK ((N_NODES + SCAN_BLOCK - 1) / SCAN_BLOCK)   // 98

__device__ inline unsigned pack_bf16x2(float lo, float hi) {
    unsigned a = __float_as_uint(lo), b = __float_as_uint(hi);
    a = (a + 0x7fffu + ((a >> 16) & 1u)) >> 16;
    b = (b + 0x7fffu + ((b >> 16) & 1u)) & 0xffff0000u;
    return a | b;
}
__device__ inline float bf_lo(unsigned u) { return __uint_as_float(u << 16); }
__device__ inline float bf_hi(unsigned u) { return __uint_as_float(u & 0xffff0000u); }

// ---------------- histogram: packed 16-bit LDS counters ----------------
__global__ __launch_bounds__(1024) void k_hist(const int* __restrict__ src,
                                               const int* __restrict__ dst,
                                               int* __restrict__ Hs,
                                               int* __restrict__ Hd) {
    __shared__ unsigned h32[RANGE_H / 2];    // 64 KB, two 16-bit counters per int
    int c = blockIdx.x, r = blockIdx.y;
    const int* a = blockIdx.z ? dst : src;
    int* H = blockIdx.z ? Hd : Hs;
    for (int k = threadIdx.x; k < RANGE_H / 2; k += 1024) h32[k] = 0;
    __syncthreads();
    int r0 = r * RANGE_H;
    int e0 = c * CHUNK, e1 = e0 + CHUNK;
    for (int e = e0 + threadIdx.x; e < e1; e += 1024) {
        unsigned d = (unsigned)(a[e] - r0);
        if (d < RANGE_H) atomicAdd(&h32[d >> 1], 1u << ((d & 1) * 16));
    }
    __syncthreads();
    for (int k = threadIdx.x; k < RANGE_H; k += 1024)
        H[c * NPAD_H + r0 + k] = (int)((h32[k >> 1] >> ((k & 1) * 16)) & 0xffffu);
}

// deg_src = column-sum of Hs; maxdeg
__global__ __launch_bounds__(256) void k_degsrc(const int* __restrict__ Hs,
                                                int* __restrict__ deg_src,
                                                int* __restrict__ maxdeg) {
    int i = blockIdx.x * 256 + threadIdx.x;
    int v = 0;
    if (i < N_NODES) {
        #pragma unroll
        for (int c = 0; c < NC; c++) v += Hs[c * NPAD_H + i];
        deg_src[i] = v;
    }
    int m = v;
    for (int off = 32; off; off >>= 1) m = max(m, __shfl_down(m, off));
    if ((threadIdx.x & 63) == 0) atomicMax(maxdeg, m);
}

// inclusive scan of deg_dst (= column-sum of Hd) -> rowptr[i+1]
__global__ __launch_bounds__(SCAN_BLOCK) void k_scan1(const int* __restrict__ Hd,
                                                      int* __restrict__ rowptr,
                                                      int* __restrict__ blocksum) {
    __shared__ int buf[2][SCAN_BLOCK];
    int t = threadIdx.x;
    int i = blockIdx.x * SCAN_BLOCK + t;
    int v = 0;
    if (i < N_NODES) {
        #pragma unroll
        for (int c = 0; c < NC; c++) v += Hd[c * NPAD_H + i];
    }
    int cur = 0;
    buf[0][t] = v;
    __syncthreads();
    for (int off = 1; off < SCAN_BLOCK; off <<= 1) {
        int nv = buf[cur][t];
        if (t >= off) nv += buf[cur][t - off];
        buf[1 - cur][t] = nv;
        cur = 1 - cur;
        __syncthreads();
    }
    int incl = buf[cur][t];
    if (i < N_NODES) rowptr[i + 1] = incl;
    if (t == SCAN_BLOCK - 1) blocksum[blockIdx.x] = incl;
}

__global__ __launch_bounds__(SCAN_BLOCK) void k_scan2(int* __restrict__ rowptr,
                                                      const int* __restrict__ blocksum) {
    __shared__ int offs[SCAN_NBLK];
    if (threadIdx.x == 0) {
        int run = 0;
        for (int b = 0; b < SCAN_NBLK; b++) { offs[b] = run; run += blocksum[b]; }
        rowptr[0] = 0;
    }
    __syncthreads();
    for (int i = threadIdx.x; i < N_NODES; i += SCAN_BLOCK)
        rowptr[i + 1] += offs[i / SCAN_BLOCK];
}

// Hd[c][d] := rowptr[d] + sum_{c'<c} Hd[c'][d]
__global__ __launch_bounds__(256) void k_basepos(const int* __restrict__ rowptr,
                                                 int* __restrict__ Hd) {
    int i = blockIdx.x * 256 + threadIdx.x;
    if (i >= N_NODES) return;
    int run = rowptr[i];
    #pragma unroll
    for (int c = 0; c < NC; c++) {
        int t = Hd[c * NPAD_H + i];
        Hd[c * NPAD_H + i] = run;
        run += t;
    }
}

// counting-sort fill: LDS position counters, no global atomics
__global__ __launch_bounds__(1024) void k_fill2(const int* __restrict__ src,
                                                const int* __restrict__ dst,
                                                const int* __restrict__ basepos,
                                                int* __restrict__ csr_src) {
    __shared__ int pos[RANGE_F];
    int c = blockIdx.x, r = blockIdx.y;
    int r0 = r * RANGE_F;
    for (int k = threadIdx.x; k < RANGE_F; k += 1024) pos[k] = basepos[c * NPAD_H + r0 + k];
    __syncthreads();
    int e0 = c * CHUNK, e1 = e0 + CHUNK;
    for (int e = e0 + threadIdx.x; e < e1; e += 1024) {
        unsigned d = (unsigned)(dst[e] - r0);
        if (d < RANGE_F) {
            int s = src[e];
            int p = atomicAdd(&pos[d], 1);
            csr_src[p] = s;
        }
    }
}

// ---------------- GEMM 64->64: G0 = h@W0+b (float2), G1b = pack_bf16(h@W1) ----------------
__global__ __launch_bounds__(256) void k_gemm64(const float* __restrict__ h,
                                                const float* __restrict__ W0,
                                                const float* __restrict__ W1,
                                                const float* __restrict__ b,
                                                float2* __restrict__ G02,
                                                unsigned* __restrict__ G1b) {
    __shared__ float2 sw0[64 * 32], sw1[64 * 32];
    __shared__ float sh[16 * 64];
    int t = threadIdx.x;
    const float2* W02 = (const float2*)W0;
    const float2* W12 = (const float2*)W1;
    for (int k = t; k < 64 * 32; k += 256) { sw0[k] = W02[k]; sw1[k] = W12[k]; }
    int i0 = blockIdx.x * 16;    // grid exactly N/16
    for (int k = t; k < 16 * 64; k += 256) sh[k] = h[i0 * 64 + k];
    __syncthreads();
    int c2 = t & 31, rg = t >> 5;          // rows rg, rg+8
    float2 b2 = ((const float2*)b)[c2];
    #pragma unroll
    for (int p = 0; p < 2; p++) {
        int row = rg + 8 * p;
        float a0x = b2.x, a0y = b2.y, a1x = 0.f, a1y = 0.f;
        #pragma unroll
        for (int k = 0; k < 64; k++) {
            float hv = sh[row * 64 + k];
            float2 w0 = sw0[k * 32 + c2];
            float2 w1 = sw1[k * 32 + c2];
            a0x += hv * w0.x; a0y += hv * w0.y;
            a1x += hv * w1.x; a1y += hv * w1.y;
        }
        int gi = (i0 + row) * 32 + c2;
        G02[gi] = make_float2(a0x, a0y);
        G1b[gi] = pack_bf16x2(a1x, a1y);
    }
}

// ---------------- GEMM 64->40 ----------------
__global__ __launch_bounds__(256) void k_gemm40(const float* __restrict__ h,
                                                const float* __restrict__ W0,
                                                const float* __restrict__ W1,
                                                const float* __restrict__ b,
                                                float2* __restrict__ G02,
                                                unsigned* __restrict__ G1b) {
    __shared__ float2 sw0[64 * PAIRS40], sw1[64 * PAIRS40];
    __shared__ float sh[16 * 64];
    int t = threadIdx.x;
    const float2* W02 = (const float2*)W0;
    const float2* W12 = (const float2*)W1;
    for (int k = t; k < 64 * PAIRS40; k += 256) { sw0[k] = W02[k]; sw1[k] = W12[k]; }
    int i0 = blockIdx.x * 16;
    for (int k = t; k < 16 * 64; k += 256) sh[k] = h[i0 * 64 + k];
    __syncthreads();
    int c2 = t & 31, rg = t >> 5;
    if (c2 >= PAIRS40) return;
    float2 b2 = ((const float2*)b)[c2];
    #pragma unroll
    for (int p = 0; p < 2; p++) {
        int row = rg + 8 * p;
        float a0x = b2.x, a0y = b2.y, a1x = 0.f, a1y = 0.f;
        #pragma unroll
        for (int k = 0; k < 64; k++) {
            float hv = sh[row * 64 + k];
            float2 w0 = sw0[k * PAIRS40 + c2];
            float2 w1 = sw1[k * PAIRS40 + c2];
            a0x += hv * w0.x; a0y += hv * w0.y;
            a1x += hv * w1.x; a1y += hv * w1.y;
        }
        int gi = (i0 + row) * PAIRS40 + c2;
        G02[gi] = make_float2(a0x, a0y);
        G1b[gi] = pack_bf16x2(a1x, a1y);
    }
}

// ---------------- fused SpMM + relu, 64 ch, 2 edges per wave-iteration ----------------
__global__ __launch_bounds__(256) void k_spmm64(const float2* __restrict__ G02,
                                                const unsigned* __restrict__ G1b,
                                                const int* __restrict__ rowptr,
                                                const int* __restrict__ csr_src,
                                                const int* __restrict__ deg_src,
                                                const int* __restrict__ maxdeg,
                                                float2* __restrict__ out2) {
    int wave = threadIdx.x >> 6;
    int lane = threadIdx.x & 63;
    int half = lane >> 5, c2 = lane & 31;
    int i = blockIdx.x * 4 + wave;
    float scale = 1.0f / (float)(*maxdeg);
    int e0 = rowptr[i], e1 = rowptr[i + 1];
    float acc0 = 0.f, acc1 = 0.f;
    for (int base = e0; base < e1; base += 64) {
        int n = min(64, e1 - base);
        int idx = (base + lane < e1) ? csr_src[base + lane] : 0;
        int j = 0;
        for (; j + 4 <= n; j += 4) {             // 4 edges per iter (2 per half)
            int sA = __shfl(idx, j + half);
            int sB = __shfl(idx, j + 2 + half);
            unsigned uA = G1b[sA * 32 + c2];
            unsigned uB = G1b[sB * 32 + c2];
            acc0 += bf_lo(uA) + bf_lo(uB);
            acc1 += bf_hi(uA) + bf_hi(uB);
        }
        for (; j < n; j += 2) {
            int s = __shfl(idx, j + half);
            bool valid = (j + half) < n;
            unsigned u = G1b[s * 32 + c2];
            if (valid) { acc0 += bf_lo(u); acc1 += bf_hi(u); }
        }
    }
    acc0 += __shfl_xor(acc0, 32);
    acc1 += __shfl_xor(acc1, 32);
    if (half == 0) {
        float2 g0 = G02[i * 32 + c2];
        unsigned ug = G1b[i * 32 + c2];
        float nl = (float)deg_src[i] * scale - 1.0f;
        float vx = g0.x + nl * bf_lo(ug) - scale * acc0;
        float vy = g0.y + nl * bf_hi(ug) - scale * acc1;
        out2[i * 32 + c2] = make_float2(fmaxf(vx, 0.f), fmaxf(vy, 0.f));
    }
}

// ---------------- fused SpMM + log_softmax, 40 ch ----------------
__global__ __launch_bounds__(256) void k_spmm40(const float2* __restrict__ G02,
                                                const unsigned* __restrict__ G1b,
                                                const int* __restrict__ rowptr,
                                                const int* __restrict__ csr_src,
                                                const int* __restrict__ deg_src,
                                                const int* __restrict__ maxdeg,
                                                float2* __restrict__ out2) {
    int wave = threadIdx.x >> 6;
    int lane = threadIdx.x & 63;
    int half = lane >> 5, c2 = lane & 31;
    bool act = c2 < PAIRS40;
    int i = blockIdx.x * 4 + wave;
    float scale = 1.0f / (float)(*maxdeg);
    int e0 = rowptr[i], e1 = rowptr[i + 1];
    float acc0 = 0.f, acc1 = 0.f;
    for (int base = e0; base < e1; base += 64) {
        int n = min(64, e1 - base);
        int idx = (base + lane < e1) ? csr_src[base + lane] : 0;
        int j = 0;
        for (; j + 4 <= n; j += 4) {
            int sA = __shfl(idx, j + half);
            int sB = __shfl(idx, j + 2 + half);
            if (act) {
                unsigned uA = G1b[sA * PAIRS40 + c2];
                unsigned uB = G1b[sB * PAIRS40 + c2];
                acc0 += bf_lo(uA) + bf_lo(uB);
                acc1 += bf_hi(uA) + bf_hi(uB);
            }
        }
        for (; j < n; j += 2) {
            int s = __shfl(idx, j + half);
            bool valid = act && (j + half) < n;
            if (valid) {
                unsigned u = G1b[s * PAIRS40 + c2];
                acc0 += bf_lo(u); acc1 += bf_hi(u);
            }
        }
    }
    acc0 += __shfl_xor(acc0, 32);
    acc1 += __shfl_xor(acc1, 32);
    // epilogue in lower half (lanes 0..31); lanes >= PAIRS40 neutral
    float vx = 0.f, vy = 0.f;
    if (act) {
        float2 g0 = G02[i * PAIRS40 + c2];
        unsigned ug = G1b[i * PAIRS40 + c2];
        float nl = (float)deg_src[i] * scale - 1.0f;
        vx = g0.x + nl * bf_lo(ug) - scale * acc0;
        vy = g0.y + nl * bf_hi(ug) - scale * acc1;
    }
    float m = act ? fmaxf(vx, vy) : -INFINITY;
    for (int off = 16; off; off >>= 1) m = fmaxf(m, __shfl_xor(m, off));
    float s = act ? (__expf(vx - m) + __expf(vy - m)) : 0.f;
    for (int off = 16; off; off >>= 1) s += __shfl_xor(s, off);
    float ls = __logf(s);
    if (act && half == 0)
        out2[i * PAIRS40 + c2] = make_float2(vx - m - ls, vy - m - ls);
}

// ---------------- launch ----------------

extern "C" void kernel_launch(void* const* d_in, const int* in_sizes, int n_in,
                              void* d_out, int out_size, void* d_ws, size_t ws_size,
                              hipStream_t stream) {
    const float* x   = (const float*)d_in[0];
    const int* ei    = (const int*)d_in[1];
    const int* src   = ei;
    const int* dst   = ei + N_EDGES;
    const float* W0_0 = (const float*)d_in[2];
    const float* W1_0 = (const float*)d_in[3];
    const float* b_0  = (const float*)d_in[4];
    const float* W0_1 = (const float*)d_in[5];
    const float* W1_1 = (const float*)d_in[6];
    const float* b_1  = (const float*)d_in[7];
    const float* W0_2 = (const float*)d_in[8];
    const float* W1_2 = (const float*)d_in[9];
    const float* b_2  = (const float*)d_in[10];
    float* outp = (float*)d_out;

    // workspace layout
    int* ip = (int*)d_ws;
    int* deg_src  = ip;                      // N
    int* rowptr   = ip + 100000;             // N+1 (padded to 100032)
    int* blocksum = ip + 200064;             // 128
    int* maxdeg   = ip + 200192;             // 1 (padded to 64)
    int* csr_src  = ip + 200256;             // E
    float* fb = (float*)(ip + 1800256);
    float* hbuf = fb;                        // N*64 fp32
    float* G0   = fb + 6400000;              // N*64 fp32 region (also Hs: NC*NPAD_H=4.19M ints)
    float* G1   = fb + 12800000;             // region (G1b: N*32 uints; also Hd: 4.19M ints)
    int* Hs = (int*)G0;
    int* Hd = (int*)G1;
    float2* G02 = (float2*)G0;
    unsigned* G1b = (unsigned*)G1;

    hipMemsetAsync(maxdeg, 0, sizeof(int), stream);

    k_hist<<<dim3(NC, NR_H, 2), 1024, 0, stream>>>(src, dst, Hs, Hd);
    k_degsrc<<<(N_NODES + 255) / 256, 256, 0, stream>>>(Hs, deg_src, maxdeg);
    k_scan1<<<SCAN_NBLK, SCAN_BLOCK, 0, stream>>>(Hd, rowptr, blocksum);
    k_scan2<<<1, SCAN_BLOCK, 0, stream>>>(rowptr, blocksum);
    k_basepos<<<(N_NODES + 255) / 256, 256, 0, stream>>>(rowptr, Hd);
    k_fill2<<<dim3(NC, NR_F), 1024, 0, stream>>>(src, dst, Hd, csr_src);

    const int GN = N_NODES / 4;    // 25000, exact
    const int GG = N_NODES / 16;   // 6250, exact

    // layer 0: x -> hbuf
    k_gemm64<<<GG, 256, 0, stream>>>(x, W0_0, W1_0, b_0, G02, G1b);
    k_spmm64<<<GN, 256, 0, stream>>>(G02, G1b, rowptr, csr_src, deg_src, maxdeg, (float2*)hbuf);
    // layer 1: hbuf -> hbuf
    k_gemm64<<<GG, 256, 0, stream>>>(hbuf, W0_1, W1_1, b_1, G02, G1b);
    k_spmm64<<<GN, 256, 0, stream>>>(G02, G1b, rowptr, csr_src, deg_src, maxdeg, (float2*)hbuf);
    // layer 2: hbuf -> out (40 ch + log_softmax)
    k_gemm40<<<GG, 256, 0, stream>>>(hbuf, W0_2, W1_2, b_2, G02, G1b);
    k_spmm40<<<GN, 256, 0, stream>>>(G02, G1b, rowptr, csr_src, deg_src, maxdeg, (float2*)outp);
}

// Round 5
// 443.327 us; speedup vs baseline: 1.2522x; 1.2522x over previous
//
#include <hip/hip_runtime.h>
#include <math.h>

#define N_NODES 100000
#define N_EDGES 1600000
#define OUTC 40
#define PAIRS40 20

#define NC 32                       // edge chunks
#define CHUNK (N_EDGES / NC)        // 50000 exact

// histogram pass: 16-bit packed counters, 32768 nodes/range
#define RANGE_H 32768
#define NR_H 4                      // 4*32768 = 131072 >= N
#define NPAD_H (NR_H * RANGE_H)     // 131072

// fill pass: 32-bit position counters, 16384 nodes/range
#define RANGE_F 16384
#define NR_F 7                      // 7*16384 = 114688 >= N

#define SCAN_BLOCK 1024
#define SCAN_NBLK ((N_NODES + SCAN_BLOCK - 1) / SCAN_BLOCK)   // 98

__device__ inline unsigned pack_bf16x2(float lo, float hi) {
    unsigned a = __float_as_uint(lo), b = __float_as_uint(hi);
    a = (a + 0x7fffu + ((a >> 16) & 1u)) >> 16;
    b = (b + 0x7fffu + ((b >> 16) & 1u)) & 0xffff0000u;
    return a | b;
}
__device__ inline float bf_lo(unsigned u) { return __uint_as_float(u << 16); }
__device__ inline float bf_hi(unsigned u) { return __uint_as_float(u & 0xffff0000u); }

// ---------------- histogram: packed 16-bit LDS counters ----------------
__global__ __launch_bounds__(1024) void k_hist(const int* __restrict__ src,
                                               const int* __restrict__ dst,
                                               int* __restrict__ Hs,
                                               int* __restrict__ Hd) {
    __shared__ unsigned h32[RANGE_H / 2];    // 64 KB, two 16-bit counters per int
    int c = blockIdx.x, r = blockIdx.y;
    const int* a = blockIdx.z ? dst : src;
    int* H = blockIdx.z ? Hd : Hs;
    for (int k = threadIdx.x; k < RANGE_H / 2; k += 1024) h32[k] = 0;
    __syncthreads();
    int r0 = r * RANGE_H;
    int e0 = c * CHUNK, e1 = e0 + CHUNK;
    for (int e = e0 + threadIdx.x; e < e1; e += 1024) {
        unsigned d = (unsigned)(a[e] - r0);
        if (d < RANGE_H) atomicAdd(&h32[d >> 1], 1u << ((d & 1) * 16));
    }
    __syncthreads();
    for (int k = threadIdx.x; k < RANGE_H; k += 1024)
        H[c * NPAD_H + r0 + k] = (int)((h32[k >> 1] >> ((k & 1) * 16)) & 0xffffu);
}

// deg_src = column-sum of Hs; maxdeg
__global__ __launch_bounds__(256) void k_degsrc(const int* __restrict__ Hs,
                                                int* __restrict__ deg_src,
                                                int* __restrict__ maxdeg) {
    int i = blockIdx.x * 256 + threadIdx.x;
    int v = 0;
    if (i < N_NODES) {
        #pragma unroll
        for (int c = 0; c < NC; c++) v += Hs[c * NPAD_H + i];
        deg_src[i] = v;
    }
    int m = v;
    for (int off = 32; off; off >>= 1) m = max(m, __shfl_down(m, off));
    if ((threadIdx.x & 63) == 0) atomicMax(maxdeg, m);
}

// inclusive scan of deg_dst (= column-sum of Hd) -> rowptr[i+1]
__global__ __launch_bounds__(SCAN_BLOCK) void k_scan1(const int* __restrict__ Hd,
                                                      int* __restrict__ rowptr,
                                                      int* __restrict__ blocksum) {
    __shared__ int buf[2][SCAN_BLOCK];
    int t = threadIdx.x;
    int i = blockIdx.x * SCAN_BLOCK + t;
    int v = 0;
    if (i < N_NODES) {
        #pragma unroll
        for (int c = 0; c < NC; c++) v += Hd[c * NPAD_H + i];
    }
    int cur = 0;
    buf[0][t] = v;
    __syncthreads();
    for (int off = 1; off < SCAN_BLOCK; off <<= 1) {
        int nv = buf[cur][t];
        if (t >= off) nv += buf[cur][t - off];
        buf[1 - cur][t] = nv;
        cur = 1 - cur;
        __syncthreads();
    }
    int incl = buf[cur][t];
    if (i < N_NODES) rowptr[i + 1] = incl;
    if (t == SCAN_BLOCK - 1) blocksum[blockIdx.x] = incl;
}

__global__ __launch_bounds__(SCAN_BLOCK) void k_scan2(int* __restrict__ rowptr,
                                                      const int* __restrict__ blocksum) {
    __shared__ int offs[SCAN_NBLK];
    if (threadIdx.x == 0) {
        int run = 0;
        for (int b = 0; b < SCAN_NBLK; b++) { offs[b] = run; run += blocksum[b]; }
        rowptr[0] = 0;
    }
    __syncthreads();
    for (int i = threadIdx.x; i < N_NODES; i += SCAN_BLOCK)
        rowptr[i + 1] += offs[i / SCAN_BLOCK];
}

// Hd[c][d] := rowptr[d] + sum_{c'<c} Hd[c'][d]
__global__ __launch_bounds__(256) void k_basepos(const int* __restrict__ rowptr,
                                                 int* __restrict__ Hd) {
    int i = blockIdx.x * 256 + threadIdx.x;
    if (i >= N_NODES) return;
    int run = rowptr[i];
    #pragma unroll
    for (int c = 0; c < NC; c++) {
        int t = Hd[c * NPAD_H + i];
        Hd[c * NPAD_H + i] = run;
        run += t;
    }
}

// counting-sort fill: LDS position counters, no global atomics
__global__ __launch_bounds__(1024) void k_fill2(const int* __restrict__ src,
                                                const int* __restrict__ dst,
                                                const int* __restrict__ basepos,
                                                int* __restrict__ csr_src) {
    __shared__ int pos[RANGE_F];
    int c = blockIdx.x, r = blockIdx.y;
    int r0 = r * RANGE_F;
    for (int k = threadIdx.x; k < RANGE_F; k += 1024) pos[k] = basepos[c * NPAD_H + r0 + k];
    __syncthreads();
    int e0 = c * CHUNK, e1 = e0 + CHUNK;
    for (int e = e0 + threadIdx.x; e < e1; e += 1024) {
        unsigned d = (unsigned)(dst[e] - r0);
        if (d < RANGE_F) {
            int s = src[e];
            int p = atomicAdd(&pos[d], 1);
            csr_src[p] = s;
        }
    }
}

// ---------------- GEMM 64->64: 32-row tile, thread = 4 rows x 2 cols ----------------
// G0 = h@W0 + b (float2), G1b = pack_bf16(h@W1)
__global__ __launch_bounds__(256) void k_gemm64(const float* __restrict__ h,
                                                const float* __restrict__ W0,
                                                const float* __restrict__ W1,
                                                const float* __restrict__ b,
                                                float2* __restrict__ G02,
                                                unsigned* __restrict__ G1b) {
    __shared__ float2 sw0[64 * 32], sw1[64 * 32];   // 32 KB
    __shared__ float sh[32 * 64];                   // 8 KB
    int t = threadIdx.x;
    const float2* W02 = (const float2*)W0;
    const float2* W12 = (const float2*)W1;
    for (int k = t; k < 64 * 32; k += 256) { sw0[k] = W02[k]; sw1[k] = W12[k]; }
    int i0 = blockIdx.x * 32;    // grid exactly N/32
    const float4* h4 = (const float4*)(h + (size_t)i0 * 64);
    float4* sh4 = (float4*)sh;
    for (int k = t; k < 512; k += 256) sh4[k] = h4[k];
    __syncthreads();
    int c2 = t & 31, rg = t >> 5;          // rows rg, rg+8, rg+16, rg+24
    float2 b2 = ((const float2*)b)[c2];
    float a0x[4], a0y[4], a1x[4], a1y[4];
    #pragma unroll
    for (int p = 0; p < 4; p++) { a0x[p] = b2.x; a0y[p] = b2.y; a1x[p] = 0.f; a1y[p] = 0.f; }
    #pragma unroll
    for (int k = 0; k < 64; k++) {
        float2 w0 = sw0[k * 32 + c2];
        float2 w1 = sw1[k * 32 + c2];
        #pragma unroll
        for (int p = 0; p < 4; p++) {
            float hv = sh[(rg + 8 * p) * 64 + k];
            a0x[p] += hv * w0.x; a0y[p] += hv * w0.y;
            a1x[p] += hv * w1.x; a1y[p] += hv * w1.y;
        }
    }
    #pragma unroll
    for (int p = 0; p < 4; p++) {
        int gi = (i0 + rg + 8 * p) * 32 + c2;
        G02[gi] = make_float2(a0x[p], a0y[p]);
        G1b[gi] = pack_bf16x2(a1x[p], a1y[p]);
    }
}

// ---------------- GEMM 64->40: same structure, 20 col-pairs active ----------------
__global__ __launch_bounds__(256) void k_gemm40(const float* __restrict__ h,
                                                const float* __restrict__ W0,
                                                const float* __restrict__ W1,
                                                const float* __restrict__ b,
                                                float2* __restrict__ G02,
                                                unsigned* __restrict__ G1b) {
    __shared__ float2 sw0[64 * PAIRS40], sw1[64 * PAIRS40];   // 20 KB
    __shared__ float sh[32 * 64];                             // 8 KB
    int t = threadIdx.x;
    const float2* W02 = (const float2*)W0;
    const float2* W12 = (const float2*)W1;
    for (int k = t; k < 64 * PAIRS40; k += 256) { sw0[k] = W02[k]; sw1[k] = W12[k]; }
    int i0 = blockIdx.x * 32;
    const float4* h4 = (const float4*)(h + (size_t)i0 * 64);
    float4* sh4 = (float4*)sh;
    for (int k = t; k < 512; k += 256) sh4[k] = h4[k];
    __syncthreads();
    int c2 = t & 31, rg = t >> 5;
    if (c2 >= PAIRS40) return;
    float2 b2 = ((const float2*)b)[c2];
    float a0x[4], a0y[4], a1x[4], a1y[4];
    #pragma unroll
    for (int p = 0; p < 4; p++) { a0x[p] = b2.x; a0y[p] = b2.y; a1x[p] = 0.f; a1y[p] = 0.f; }
    #pragma unroll
    for (int k = 0; k < 64; k++) {
        float2 w0 = sw0[k * PAIRS40 + c2];
        float2 w1 = sw1[k * PAIRS40 + c2];
        #pragma unroll
        for (int p = 0; p < 4; p++) {
            float hv = sh[(rg + 8 * p) * 64 + k];
            a0x[p] += hv * w0.x; a0y[p] += hv * w0.y;
            a1x[p] += hv * w1.x; a1y[p] += hv * w1.y;
        }
    }
    #pragma unroll
    for (int p = 0; p < 4; p++) {
        int gi = (i0 + rg + 8 * p) * PAIRS40 + c2;
        G02[gi] = make_float2(a0x[p], a0y[p]);
        G1b[gi] = pack_bf16x2(a1x[p], a1y[p]);
    }
}

// ---------------- fused SpMM + relu, 64 ch, 2 edges per wave-iteration ----------------
__global__ __launch_bounds__(256) void k_spmm64(const float2* __restrict__ G02,
                                                const unsigned* __restrict__ G1b,
                                                const int* __restrict__ rowptr,
                                                const int* __restrict__ csr_src,
                                                const int* __restrict__ deg_src,
                                                const int* __restrict__ maxdeg,
                                                float2* __restrict__ out2) {
    int wave = threadIdx.x >> 6;
    int lane = threadIdx.x & 63;
    int half = lane >> 5, c2 = lane & 31;
    int i = blockIdx.x * 4 + wave;
    float scale = 1.0f / (float)(*maxdeg);
    int e0 = rowptr[i], e1 = rowptr[i + 1];
    float acc0 = 0.f, acc1 = 0.f;
    for (int base = e0; base < e1; base += 64) {
        int n = min(64, e1 - base);
        int idx = (base + lane < e1) ? csr_src[base + lane] : 0;
        int j = 0;
        for (; j + 4 <= n; j += 4) {             // 4 edges per iter (2 per half)
            int sA = __shfl(idx, j + half);
            int sB = __shfl(idx, j + 2 + half);
            unsigned uA = G1b[sA * 32 + c2];
            unsigned uB = G1b[sB * 32 + c2];
            acc0 += bf_lo(uA) + bf_lo(uB);
            acc1 += bf_hi(uA) + bf_hi(uB);
        }
        for (; j < n; j += 2) {
            int s = __shfl(idx, j + half);
            bool valid = (j + half) < n;
            unsigned u = G1b[s * 32 + c2];
            if (valid) { acc0 += bf_lo(u); acc1 += bf_hi(u); }
        }
    }
    acc0 += __shfl_xor(acc0, 32);
    acc1 += __shfl_xor(acc1, 32);
    if (half == 0) {
        float2 g0 = G02[i * 32 + c2];
        unsigned ug = G1b[i * 32 + c2];
        float nl = (float)deg_src[i] * scale - 1.0f;
        float vx = g0.x + nl * bf_lo(ug) - scale * acc0;
        float vy = g0.y + nl * bf_hi(ug) - scale * acc1;
        out2[i * 32 + c2] = make_float2(fmaxf(vx, 0.f), fmaxf(vy, 0.f));
    }
}

// ---------------- fused SpMM + log_softmax, 40 ch ----------------
__global__ __launch_bounds__(256) void k_spmm40(const float2* __restrict__ G02,
                                                const unsigned* __restrict__ G1b,
                                                const int* __restrict__ rowptr,
                                                const int* __restrict__ csr_src,
                                                const int* __restrict__ deg_src,
                                                const int* __restrict__ maxdeg,
                                                float2* __restrict__ out2) {
    int wave = threadIdx.x >> 6;
    int lane = threadIdx.x & 63;
    int half = lane >> 5, c2 = lane & 31;
    bool act = c2 < PAIRS40;
    int i = blockIdx.x * 4 + wave;
    float scale = 1.0f / (float)(*maxdeg);
    int e0 = rowptr[i], e1 = rowptr[i + 1];
    float acc0 = 0.f, acc1 = 0.f;
    for (int base = e0; base < e1; base += 64) {
        int n = min(64, e1 - base);
        int idx = (base + lane < e1) ? csr_src[base + lane] : 0;
        int j = 0;
        for (; j + 4 <= n; j += 4) {
            int sA = __shfl(idx, j + half);
            int sB = __shfl(idx, j + 2 + half);
            if (act) {
                unsigned uA = G1b[sA * PAIRS40 + c2];
                unsigned uB = G1b[sB * PAIRS40 + c2];
                acc0 += bf_lo(uA) + bf_lo(uB);
                acc1 += bf_hi(uA) + bf_hi(uB);
            }
        }
        for (; j < n; j += 2) {
            int s = __shfl(idx, j + half);
            bool valid = act && (j + half) < n;
            if (valid) {
                unsigned u = G1b[s * PAIRS40 + c2];
                acc0 += bf_lo(u); acc1 += bf_hi(u);
            }
        }
    }
    acc0 += __shfl_xor(acc0, 32);
    acc1 += __shfl_xor(acc1, 32);
    float vx = 0.f, vy = 0.f;
    if (act) {
        float2 g0 = G02[i * PAIRS40 + c2];
        unsigned ug = G1b[i * PAIRS40 + c2];
        float nl = (float)deg_src[i] * scale - 1.0f;
        vx = g0.x + nl * bf_lo(ug) - scale * acc0;
        vy = g0.y + nl * bf_hi(ug) - scale * acc1;
    }
    float m = act ? fmaxf(vx, vy) : -INFINITY;
    for (int off = 16; off; off >>= 1) m = fmaxf(m, __shfl_xor(m, off));
    float s = act ? (__expf(vx - m) + __expf(vy - m)) : 0.f;
    for (int off = 16; off; off >>= 1) s += __shfl_xor(s, off);
    float ls = __logf(s);
    if (act && half == 0)
        out2[i * PAIRS40 + c2] = make_float2(vx - m - ls, vy - m - ls);
}

// ---------------- launch ----------------

extern "C" void kernel_launch(void* const* d_in, const int* in_sizes, int n_in,
                              void* d_out, int out_size, void* d_ws, size_t ws_size,
                              hipStream_t stream) {
    const float* x   = (const float*)d_in[0];
    const int* ei    = (const int*)d_in[1];
    const int* src   = ei;
    const int* dst   = ei + N_EDGES;
    const float* W0_0 = (const float*)d_in[2];
    const float* W1_0 = (const float*)d_in[3];
    const float* b_0  = (const float*)d_in[4];
    const float* W0_1 = (const float*)d_in[5];
    const float* W1_1 = (const float*)d_in[6];
    const float* b_1  = (const float*)d_in[7];
    const float* W0_2 = (const float*)d_in[8];
    const float* W1_2 = (const float*)d_in[9];
    const float* b_2  = (const float*)d_in[10];
    float* outp = (float*)d_out;

    // workspace layout
    int* ip = (int*)d_ws;
    int* deg_src  = ip;                      // N
    int* rowptr   = ip + 100000;             // N+1 (padded to 100032)
    int* blocksum = ip + 200064;             // 128
    int* maxdeg   = ip + 200192;             // 1 (padded to 64)
    int* csr_src  = ip + 200256;             // E
    float* fb = (float*)(ip + 1800256);
    float* hbuf = fb;                        // N*64 fp32
    float* G0   = fb + 6400000;              // region (also Hs: NC*NPAD_H=4.19M ints)
    float* G1   = fb + 12800000;             // region (G1b: N*32 uints; also Hd)
    int* Hs = (int*)G0;
    int* Hd = (int*)G1;
    float2* G02 = (float2*)G0;
    unsigned* G1b = (unsigned*)G1;

    hipMemsetAsync(maxdeg, 0, sizeof(int), stream);

    k_hist<<<dim3(NC, NR_H, 2), 1024, 0, stream>>>(src, dst, Hs, Hd);
    k_degsrc<<<(N_NODES + 255) / 256, 256, 0, stream>>>(Hs, deg_src, maxdeg);
    k_scan1<<<SCAN_NBLK, SCAN_BLOCK, 0, stream>>>(Hd, rowptr, blocksum);
    k_scan2<<<1, SCAN_BLOCK, 0, stream>>>(rowptr, blocksum);
    k_basepos<<<(N_NODES + 255) / 256, 256, 0, stream>>>(rowptr, Hd);
    k_fill2<<<dim3(NC, NR_F), 1024, 0, stream>>>(src, dst, Hd, csr_src);

    const int GN = N_NODES / 4;    // 25000, exact
    const int GG = N_NODES / 32;   // 3125, exact

    // layer 0: x -> hbuf
    k_gemm64<<<GG, 256, 0, stream>>>(x, W0_0, W1_0, b_0, G02, G1b);
    k_spmm64<<<GN, 256, 0, stream>>>(G02, G1b, rowptr, csr_src, deg_src, maxdeg, (float2*)hbuf);
    // layer 1: hbuf -> hbuf
    k_gemm64<<<GG, 256, 0, stream>>>(hbuf, W0_1, W1_1, b_1, G02, G1b);
    k_spmm64<<<GN, 256, 0, stream>>>(G02, G1b, rowptr, csr_src, deg_src, maxdeg, (float2*)hbuf);
    // layer 2: hbuf -> out (40 ch + log_softmax)
    k_gemm40<<<GG, 256, 0, stream>>>(hbuf, W0_2, W1_2, b_2, G02, G1b);
    k_spmm40<<<GN, 256, 0, stream>>>(G02, G1b, rowptr, csr_src, deg_src, maxdeg, (float2*)outp);
}